// Round 10
// baseline (336.905 us; speedup 1.0000x reference)
//
#include <hip/hip_runtime.h>

#define D 128
#define NN 100000
#define PB 391          // coarse buckets: dst >> 8
#define EPB 4096        // edges per partition block (r8 proved 1024 regresses)
#define PREP_BLKS 6506  // 6250 cvt + 256 wt

typedef __attribute__((ext_vector_type(8))) short short8;
typedef __attribute__((ext_vector_type(16))) float floatx16;
typedef __attribute__((ext_vector_type(2))) float floatx2;

__device__ inline unsigned short bf16_rne(float f) {
    unsigned int u = __float_as_uint(f);
    u += 0x7fff + ((u >> 16) & 1);
    return (unsigned short)(u >> 16);
}
__device__ inline unsigned char fp8_enc1(float f) {
    return (unsigned char)(__builtin_amdgcn_cvt_pk_fp8_f32(f, f, 0, false) & 0xff);
}

// ---------------------------------------------------------------------------
// F-layout (MFMA A-fragment order) for a [N][128] bf16 matrix:
//   F(n,d) = (n>>5)*4096 + ((d>>3)*32 + (n&31))*8 + (d&7)      [elements]
// A-fragment load for 32x32x16 MFMA is tile_base + kc*512 + lane*8 ->
// linear 1KB coalesced wave load.
//
// LESSONS ENCODED:
//  * r5: write regions must be dispatch-disjoint from read regions.
//  * r6: gather is latency-bound -> needs MANY blocks (TLP), not fusion.
//  * r7: gather F-store scatter immaterial; gather FETCH ~79MB is compulsory
//    XCD replication of the fp8 table; gather ~40us is near random-access floor.
//  * r8: EPB=1024 regressed prep_count 2x (flush overhead) -> EPB=4096.
//  * r9: mfma K-loop latency-bound (16 serial A-load steps, VGPR 84 ->
//    ~2-step pipeline). r10: hoist all 16 A-frags (linear loads! r3's hoist
//    failed only because loads were scattered) -> 1 exposed latency.
// ---------------------------------------------------------------------------

// Fused prep+count: [0,6250) cvt feat->bf16(F-layout)+fp8 | [6250,6506)
// build Wt in B-fragment order | [6506, 6506+nblk) coarse edge count.
__global__ __launch_bounds__(256) void prep_count_kernel(
    const float* __restrict__ feat, unsigned short* __restrict__ feat16,
    unsigned char* __restrict__ feat8,
    const float* __restrict__ Ws0, const float* __restrict__ Wn0,
    const float* __restrict__ Ws1, const float* __restrict__ Wn1,
    unsigned short* __restrict__ wt0, unsigned short* __restrict__ wt1,
    const int* __restrict__ dst, unsigned int* __restrict__ bucketCnt,
    unsigned int* __restrict__ blockBase, int E)
{
    __shared__ unsigned int h[PB];
    int bid = blockIdx.x;
    if (bid < 6250) {
        int i = bid * 256 + threadIdx.x;      // 0..1.6M  (n*16 + c8)
        int n  = i >> 4;
        int c8 = i & 15;                      // 8-elem chunk within row
        const float* src = feat + (size_t)n * D + c8 * 8;
        float4 v0 = *(const float4*)(src);
        float4 v1 = *(const float4*)(src + 4);
        unsigned short us[8] = {
            bf16_rne(v0.x), bf16_rne(v0.y), bf16_rne(v0.z), bf16_rne(v0.w),
            bf16_rne(v1.x), bf16_rne(v1.y), bf16_rne(v1.z), bf16_rne(v1.w) };
        // F-layout: d = c8*8 -> (d>>3)=c8, d&7 spans the 16B chunk
        size_t fo = (size_t)(n >> 5) * 4096 + ((size_t)c8 * 32 + (n & 31)) * 8;
        *(uint4*)(feat16 + fo) = *(const uint4*)us;
        int w0 = __builtin_amdgcn_cvt_pk_fp8_f32(v0.x, v0.y, 0, false);
        w0 = __builtin_amdgcn_cvt_pk_fp8_f32(v0.z, v0.w, w0, true);
        int w1 = __builtin_amdgcn_cvt_pk_fp8_f32(v1.x, v1.y, 0, false);
        w1 = __builtin_amdgcn_cvt_pk_fp8_f32(v1.z, v1.w, w1, true);
        uint2 w = { (unsigned int)w0, (unsigned int)w1 };
        *(uint2*)(feat8 + (size_t)n * D + c8 * 8) = w;   // row-major, coalesced
    } else if (bid < PREP_BLKS) {
        int i = (bid - 6250) * 256 + threadIdx.x;        // 0..65535
        int layer = i >> 15;
        int r = i & 32767;
        int n = r >> 8;
        int k = r & 255;
        const float* Ws = layer ? Ws1 : Ws0;
        const float* Wn = layer ? Wn1 : Wn0;
        float v = (k < 128) ? Ws[(size_t)k * 128 + n] : Wn[(size_t)(k - 128) * 128 + n];
        unsigned short* wt = layer ? wt1 : wt0;
        // B-fragment order
        int ct = n >> 5, nn = n & 31;
        int hs = k >> 7, k7 = k & 127;
        int kc = k7 >> 4, hf = (k7 >> 3) & 1, j = k7 & 7;
        int frag = ((((ct * 2 + hs) * 8 + kc) * 2 + hf) * 32 + nn) * 8 + j;
        wt[frag] = bf16_rne(v);
    } else {
        const int b = bid - PREP_BLKS;
        const int t = threadIdx.x;
        for (int i = t; i < PB; i += 256) h[i] = 0;
        __syncthreads();
        const int base = b * EPB;
#pragma unroll
        for (int k = 0; k < EPB / 256; k++) {
            int e = base + k * 256 + t;
            if (e < E) atomicAdd(&h[(unsigned)dst[e] >> 8], 1u);
        }
        __syncthreads();
        for (int i = t; i < PB; i += 256) {
            unsigned int c = h[i];
            unsigned int o = 0;
            if (c) o = atomicAdd(&bucketCnt[i], c);
            blockBase[(size_t)b * PB + i] = o;
        }
    }
}

// single block: exclusive scan of PB bucket counts -> bucketStart[PB+1]
__global__ __launch_bounds__(512) void part_scan_kernel(
    const unsigned int* __restrict__ bucketCnt, unsigned int* __restrict__ bucketStart,
    int E)
{
    __shared__ unsigned int sd[512];
    int t = threadIdx.x;
    unsigned int v = (t < PB) ? bucketCnt[t] : 0u;
    sd[t] = v; __syncthreads();
    for (int off = 1; off < 512; off <<= 1) {
        unsigned int x = (t >= off) ? sd[t - off] : 0u;
        __syncthreads();
        sd[t] += x;
        __syncthreads();
    }
    if (t < PB) bucketStart[t] = sd[t] - v;
    if (t == 0) bucketStart[PB] = (unsigned int)E;
}

// P2: scatter packed (src<<8 | dst&255) into bucket regions; ranks via LDS.
__global__ __launch_bounds__(256) void part_scatter_kernel(
    const int* __restrict__ src, const int* __restrict__ dst,
    const unsigned int* __restrict__ bucketStart,
    const unsigned int* __restrict__ blockBase,
    unsigned int* __restrict__ pairs, int E)
{
    __shared__ unsigned int h[PB];
    const int t = threadIdx.x;
    const int b = blockIdx.x;
    for (int i = t; i < PB; i += 256) h[i] = 0;
    __syncthreads();
    const int base = b * EPB;
#pragma unroll
    for (int k = 0; k < EPB / 256; k++) {
        int e = base + k * 256 + t;
        if (e < E) {
            unsigned int d = (unsigned int)dst[e];
            unsigned int bk = d >> 8;
            unsigned int lr = atomicAdd(&h[bk], 1u);
            unsigned int pos = bucketStart[bk] + blockBase[(size_t)b * PB + bk] + lr;
            pairs[pos] = ((unsigned int)src[e] << 8) | (d & 255u);
        }
    }
}

// P3: per-bucket fine CSR (256 dsts): LDS hist + scan -> row_ptr, cursor -> col.
__global__ __launch_bounds__(256) void part_fine_kernel(
    const unsigned int* __restrict__ pairs, const unsigned int* __restrict__ bucketStart,
    int* __restrict__ row_ptr, int* __restrict__ col, int N, int E)
{
    __shared__ unsigned int h[256], sc[256], pos[256];
    const int t = threadIdx.x;
    const int b = blockIdx.x;
    h[t] = 0;
    __syncthreads();
    const unsigned int ebeg = bucketStart[b];
    const unsigned int eend = bucketStart[b + 1];
    for (unsigned int i = ebeg + t; i < eend; i += 256)
        atomicAdd(&h[pairs[i] & 255u], 1u);
    __syncthreads();
    sc[t] = h[t]; __syncthreads();
    for (int off = 1; off < 256; off <<= 1) {
        unsigned int x = (t >= off) ? sc[t - off] : 0u;
        __syncthreads();
        sc[t] += x;
        __syncthreads();
    }
    unsigned int excl = sc[t] - h[t];
    int node = b * 256 + t;
    if (node < N) row_ptr[node] = (int)(ebeg + excl);
    pos[t] = ebeg + excl;
    if (b == 0 && t == 0) row_ptr[N] = E;
    __syncthreads();
    for (unsigned int i = ebeg + t; i < eend; i += 256) {
        unsigned int p = pairs[i];
        unsigned int w = atomicAdd(&pos[p & 255u], 1u);
        col[w] = (int)(p >> 8);
    }
}

// ---------------------------------------------------------------------------
// Gather -> F-layout, 16 nodes/block (6250 blocks), one node per 16-lane
// group, NO LDS / NO barrier. 8-deep load batches + packed floatx2 accum.
// Direct 16B F-store per lane.
// ---------------------------------------------------------------------------
__global__ __launch_bounds__(256, 6) void gather16f_kernel(
    const unsigned char* __restrict__ h8, const int* __restrict__ row_ptr,
    const int* __restrict__ col, const int* __restrict__ in_deg,
    unsigned short* __restrict__ msg16, int N)   // msg16: F-layout base
{
    const int tid  = threadIdx.x;
    const int nq   = tid >> 4;        // 0..15
    const int ln16 = tid & 15;
    const int node = blockIdx.x * 16 + nq;
    if (node >= N) return;
    const size_t lo = (size_t)ln16 * 8;   // byte offset within 128B fp8 row

    int beg = row_ptr[node];
    int end = row_ptr[node + 1];

    floatx2 a0 = {0.f, 0.f}, a1 = {0.f, 0.f}, a2 = {0.f, 0.f}, a3 = {0.f, 0.f};
    int j = beg;
    for (; j + 8 <= end; j += 8) {
        int c0 = col[j],     c1 = col[j + 1], c2 = col[j + 2], c3 = col[j + 3];
        int c4 = col[j + 4], c5 = col[j + 5], c6 = col[j + 6], c7 = col[j + 7];
        uint2 u0 = *(const uint2*)(h8 + (size_t)c0 * D + lo);
        uint2 u1 = *(const uint2*)(h8 + (size_t)c1 * D + lo);
        uint2 u2 = *(const uint2*)(h8 + (size_t)c2 * D + lo);
        uint2 u3 = *(const uint2*)(h8 + (size_t)c3 * D + lo);
        uint2 u4 = *(const uint2*)(h8 + (size_t)c4 * D + lo);
        uint2 u5 = *(const uint2*)(h8 + (size_t)c5 * D + lo);
        uint2 u6 = *(const uint2*)(h8 + (size_t)c6 * D + lo);
        uint2 u7 = *(const uint2*)(h8 + (size_t)c7 * D + lo);
#pragma unroll
        for (int q = 0; q < 8; q++) {
            uint2 u = q == 0 ? u0 : q == 1 ? u1 : q == 2 ? u2 : q == 3 ? u3
                    : q == 4 ? u4 : q == 5 ? u5 : q == 6 ? u6 : u7;
            a0 += __builtin_amdgcn_cvt_pk_f32_fp8((int)u.x, false);
            a1 += __builtin_amdgcn_cvt_pk_f32_fp8((int)u.x, true);
            a2 += __builtin_amdgcn_cvt_pk_f32_fp8((int)u.y, false);
            a3 += __builtin_amdgcn_cvt_pk_f32_fp8((int)u.y, true);
        }
    }
    for (; j + 4 <= end; j += 4) {
        int c0 = col[j], c1 = col[j + 1], c2 = col[j + 2], c3 = col[j + 3];
        uint2 u0 = *(const uint2*)(h8 + (size_t)c0 * D + lo);
        uint2 u1 = *(const uint2*)(h8 + (size_t)c1 * D + lo);
        uint2 u2 = *(const uint2*)(h8 + (size_t)c2 * D + lo);
        uint2 u3 = *(const uint2*)(h8 + (size_t)c3 * D + lo);
#pragma unroll
        for (int q = 0; q < 4; q++) {
            uint2 u = q == 0 ? u0 : q == 1 ? u1 : q == 2 ? u2 : u3;
            a0 += __builtin_amdgcn_cvt_pk_f32_fp8((int)u.x, false);
            a1 += __builtin_amdgcn_cvt_pk_f32_fp8((int)u.x, true);
            a2 += __builtin_amdgcn_cvt_pk_f32_fp8((int)u.y, false);
            a3 += __builtin_amdgcn_cvt_pk_f32_fp8((int)u.y, true);
        }
    }
    for (; j < end; ++j) {
        uint2 u = *(const uint2*)(h8 + (size_t)col[j] * D + lo);
        a0 += __builtin_amdgcn_cvt_pk_f32_fp8((int)u.x, false);
        a1 += __builtin_amdgcn_cvt_pk_f32_fp8((int)u.x, true);
        a2 += __builtin_amdgcn_cvt_pk_f32_fp8((int)u.y, false);
        a3 += __builtin_amdgcn_cvt_pk_f32_fp8((int)u.y, true);
    }

    int dg = in_deg[node];
    float invd = 1.f / (float)(dg > 1 ? dg : 1);
    unsigned short us[8];
    us[0] = bf16_rne(a0.x * invd); us[1] = bf16_rne(a0.y * invd);
    us[2] = bf16_rne(a1.x * invd); us[3] = bf16_rne(a1.y * invd);
    us[4] = bf16_rne(a2.x * invd); us[5] = bf16_rne(a2.y * invd);
    us[6] = bf16_rne(a3.x * invd); us[7] = bf16_rne(a3.y * invd);
    // F-layout store: d0 = ln16*8 -> (d0>>3)=ln16, j contiguous
    size_t fo = (size_t)(node >> 5) * 4096 + ((size_t)ln16 * 32 + (node & 31)) * 8;
    *(uint4*)(msg16 + fo) = *(const uint4*)us;
}

// ---------------------------------------------------------------------------
// Layer-0 MFMA dual-GEMM + LN/ReLU. r10: all 16 A-fragments hoisted into
// registers up front (16 independent LINEAR 1KB wave loads -> one exposed
// latency; r3's hoist failed only because its loads were scattered). K-loop
// then touches only the L2-hot B table + registers. (256,3): VGPR cap 170,
// expect ~150 (a0/a1 = 64 + acc 64 unified + temps).
// C/D: col=lane&31, row=(reg&3)+8*(reg>>2)+4*(lane>>5).
// ---------------------------------------------------------------------------
__global__ __launch_bounds__(256, 3) void mfma32_ln_kernel(
    const unsigned short* __restrict__ A16, const unsigned short* __restrict__ Msg16,
    const unsigned short* __restrict__ Wt,   // B-fragment order, 32768 bf16
    const float* __restrict__ bias,
    const float* __restrict__ ln_g, const float* __restrict__ ln_b,
    unsigned short* __restrict__ Out16, unsigned char* __restrict__ Out8,
    int N)
{
    __shared__ char smem[49152];   // [0,32K): sO16 (F-order), [32K,48K): sO8

    const int tid  = threadIdx.x;
    const int wave = tid >> 6;
    const int lane = tid & 63;
    const int half = lane >> 5;
    const int n32  = lane & 31;
    const int brow0 = blockIdx.x * 128;
    const int wrow0 = brow0 + wave * 32;

    const int NT = N >> 5;
    int tile = wrow0 >> 5;
    if (tile >= NT) tile = NT - 1;           // clamp: stores guarded below
    const short8* Af = (const short8*)(A16   + (size_t)tile * 4096);
    const short8* Mf = (const short8*)(Msg16 + (size_t)tile * 4096);

    // ---- hoist all 16 A-fragments: 16 independent coalesced 1KB loads ----
    short8 a0[8], a1[8];
#pragma unroll
    for (int kc = 0; kc < 8; kc++) a0[kc] = Af[kc * 64 + lane];
#pragma unroll
    for (int kc = 0; kc < 8; kc++) a1[kc] = Mf[kc * 64 + lane];
    asm volatile("" ::: "memory");   // keep loads issued up front

    floatx16 acc[4];
#pragma unroll
    for (int ct = 0; ct < 4; ct++)
#pragma unroll
        for (int r = 0; r < 16; r++) acc[ct][r] = 0.f;

    // ---- K-loop: B (L2-hot) + registers only ----
#pragma unroll
    for (int kc = 0; kc < 8; kc++)
#pragma unroll
        for (int ct = 0; ct < 4; ct++) {
            short8 b = *(const short8*)(Wt + ((size_t)((ct * 2 + 0) * 8 + kc) * 64 + lane) * 8);
            acc[ct] = __builtin_amdgcn_mfma_f32_32x32x16_bf16(a0[kc], b, acc[ct], 0, 0, 0);
        }
#pragma unroll
    for (int kc = 0; kc < 8; kc++)
#pragma unroll
        for (int ct = 0; ct < 4; ct++) {
            short8 b = *(const short8*)(Wt + ((size_t)((ct * 2 + 1) * 8 + kc) * 64 + lane) * 8);
            acc[ct] = __builtin_amdgcn_mfma_f32_32x32x16_bf16(a1[kc], b, acc[ct], 0, 0, 0);
        }

    float bb[4], gg[4], be[4];
#pragma unroll
    for (int ct = 0; ct < 4; ct++) {
        bb[ct] = bias[ct * 32 + n32];
        gg[ct] = ln_g[ct * 32 + n32];
        be[ct] = ln_b[ct * 32 + n32];
    }
    float v[4][16];
#pragma unroll
    for (int ct = 0; ct < 4; ct++)
#pragma unroll
        for (int r = 0; r < 16; r++) v[ct][r] = acc[ct][r] + bb[ct];

    float s[16], s2[16];
#pragma unroll
    for (int r = 0; r < 16; r++) {
        s[r]  = v[0][r] + v[1][r] + v[2][r] + v[3][r];
        s2[r] = v[0][r]*v[0][r] + v[1][r]*v[1][r] + v[2][r]*v[2][r] + v[3][r]*v[3][r];
    }
#pragma unroll
    for (int off = 1; off < 32; off <<= 1) {
#pragma unroll
        for (int r = 0; r < 16; r++) {
            s[r]  += __shfl_xor(s[r],  off);
            s2[r] += __shfl_xor(s2[r], off);
        }
    }
    unsigned char* sO8 = (unsigned char*)smem + 32768;       // [128][128] byte
#pragma unroll
    for (int r = 0; r < 16; r++) {
        float mean = s[r] * (1.f / 128.f);
        float var  = s2[r] * (1.f / 128.f) - mean * mean;
        float rstd = rsqrtf(var + 1e-5f);
        int brow = wave * 32 + (r & 3) + 8 * (r >> 2) + 4 * half;
#pragma unroll
        for (int ct = 0; ct < 4; ct++) {
            float t = (v[ct][r] - mean) * rstd * gg[ct] + be[ct];
            t = t > 0.f ? t : 0.f;
            // sO16 in F-order with XOR slot swizzle (conflict-free 2B writes)
            int slot = (ct * 4 + (n32 >> 3)) ^ (brow & 15);
            *(unsigned short*)(smem + brow * 256 + slot * 16 + (n32 & 7) * 2) = bf16_rne(t);
            sO8[brow * 128 + ct * 32 + n32] = fp8_enc1(t);
        }
    }
    __syncthreads();
    // Out16 (F-layout): linear global writes; LDS reads de-swizzled
#pragma unroll
    for (int i = 0; i < 8; i++) {                 // 2048 uint4 chunks
        int ch = tid + i * 256;
        int tl = ch >> 9, p = ch & 511, kc2 = p >> 5, rr = p & 31;
        if (brow0 + tl * 32 + rr < N)
            *(uint4*)(Out16 + (size_t)brow0 * D + ch * 8) =
                *(const uint4*)&smem[(tl * 32 + rr) * 256 + ((kc2 ^ (rr & 15)) * 16)];
    }
#pragma unroll
    for (int i = 0; i < 4; i++) {                 // fp8: 1024 uint4 chunks
        int ch = tid + i * 256;
        if (brow0 + (ch >> 3) < N)
            *(uint4*)(Out8 + (size_t)brow0 * D + ch * 16) = *(const uint4*)&sO8[ch * 16];
    }
}

// ---------------------------------------------------------------------------
// Layer-1 MFMA dual-GEMM, fp32 out: NO LDS, same 16-fragment A-hoist,
// (256,3). Barrier-free; direct full-128B-line stores.
// ---------------------------------------------------------------------------
__global__ __launch_bounds__(256, 3) void mfma32_f32_kernel(
    const unsigned short* __restrict__ A16, const unsigned short* __restrict__ Msg16,
    const unsigned short* __restrict__ Wt,
    const float* __restrict__ bias,
    float* __restrict__ Out32, int N)
{
    const int tid  = threadIdx.x;
    const int wave = tid >> 6;
    const int lane = tid & 63;
    const int half = lane >> 5;
    const int n32  = lane & 31;
    const int brow0 = blockIdx.x * 128;
    const int wrow0 = brow0 + wave * 32;

    const int NT = N >> 5;
    int tile = wrow0 >> 5;
    if (tile >= NT) tile = NT - 1;
    const short8* Af = (const short8*)(A16   + (size_t)tile * 4096);
    const short8* Mf = (const short8*)(Msg16 + (size_t)tile * 4096);

    // ---- hoist all 16 A-fragments ----
    short8 a0[8], a1[8];
#pragma unroll
    for (int kc = 0; kc < 8; kc++) a0[kc] = Af[kc * 64 + lane];
#pragma unroll
    for (int kc = 0; kc < 8; kc++) a1[kc] = Mf[kc * 64 + lane];
    asm volatile("" ::: "memory");

    floatx16 acc[4];
#pragma unroll
    for (int ct = 0; ct < 4; ct++)
#pragma unroll
        for (int r = 0; r < 16; r++) acc[ct][r] = 0.f;

#pragma unroll
    for (int kc = 0; kc < 8; kc++)
#pragma unroll
        for (int ct = 0; ct < 4; ct++) {
            short8 b = *(const short8*)(Wt + ((size_t)((ct * 2 + 0) * 8 + kc) * 64 + lane) * 8);
            acc[ct] = __builtin_amdgcn_mfma_f32_32x32x16_bf16(a0[kc], b, acc[ct], 0, 0, 0);
        }
#pragma unroll
    for (int kc = 0; kc < 8; kc++)
#pragma unroll
        for (int ct = 0; ct < 4; ct++) {
            short8 b = *(const short8*)(Wt + ((size_t)((ct * 2 + 1) * 8 + kc) * 64 + lane) * 8);
            acc[ct] = __builtin_amdgcn_mfma_f32_32x32x16_bf16(a1[kc], b, acc[ct], 0, 0, 0);
        }

    float bb[4];
#pragma unroll
    for (int ct = 0; ct < 4; ct++) bb[ct] = bias[ct * 32 + n32];

#pragma unroll
    for (int r = 0; r < 16; r++) {
        int row = wrow0 + (r & 3) + 8 * (r >> 2) + 4 * half;
        if (row < N) {
#pragma unroll
            for (int ct = 0; ct < 4; ct++)
                Out32[(size_t)row * D + ct * 32 + n32] = acc[ct][r] + bb[ct];
        }
    }
}

// ---------------------------------------------------------------------------
extern "C" void kernel_launch(void* const* d_in, const int* in_sizes, int n_in,
                              void* d_out, int out_size, void* d_ws, size_t ws_size,
                              hipStream_t stream)
{
    const float* feat = (const float*)d_in[0];
    const float* Ws0  = (const float*)d_in[1];
    const float* Wn0  = (const float*)d_in[2];
    const float* b0   = (const float*)d_in[3];
    const float* Ws1  = (const float*)d_in[4];
    const float* Wn1  = (const float*)d_in[5];
    const float* b1   = (const float*)d_in[6];
    const float* lng  = (const float*)d_in[7];
    const float* lnb  = (const float*)d_in[8];
    const int* esrc   = (const int*)d_in[9];
    const int* edst   = (const int*)d_in[10];
    const int* indeg  = (const int*)d_in[11];

    const int N = NN;
    const int E = in_sizes[9];

    float* out = (float*)d_out;

    // ws: feat16 | col | row_ptr | wt0 | wt1 | regD
    //   regD overlay (CSR build): bucketCnt | bucketStart | blockBase | pairs
    //   regD overlay (compute):   h1_16
    // d_out overlay (dead until final dispatch):
    //   [0,25.6M): msg0 | [25.6M,38.4M): feat8 | [38.4M,51.2M): h18
    // Dispatch-level safety (each line: reads -> writes, all disjoint):
    //   g16f L0:  feat8, CSR           -> msg0
    //   mfma L0:  feat16, msg0, wt0    -> h116(ws), h18
    //   g16f L1:  h18, CSR             -> msg1F (=feat16 region, dead)
    //   mfma L1:  h116, msg1F, wt1     -> out (msg0/feat8/h18 all dead)
    const int nblk = (E + EPB - 1) / EPB;
    char* ws = (char*)d_ws;
    size_t o = 0;
    auto alloc = [&](size_t bytes) { char* p = ws + o; o += (bytes + 15) & ~(size_t)15; return p; };
    unsigned short* feat16 = (unsigned short*)alloc((size_t)N * D * 2);
    int* col     = (int*)alloc((size_t)E * 4);
    int* row_ptr = (int*)alloc((size_t)(N + 1) * 4);
    unsigned short* wt0 = (unsigned short*)alloc(128 * 256 * 2);
    unsigned short* wt1 = (unsigned short*)alloc(128 * 256 * 2);
    size_t csr_bytes = (size_t)(512 + 512 + (size_t)nblk * PB + E) * 4 + 64;
    char* regD = alloc((size_t)N * D * 2 > csr_bytes ? (size_t)N * D * 2 : csr_bytes);
    unsigned int* bucketCnt   = (unsigned int*)regD;                  // 512 slots
    unsigned int* bucketStart = bucketCnt + 512;                      // 512 slots
    unsigned int* blockBase   = bucketStart + 512;                    // nblk*PB
    unsigned int* pairs       = blockBase + (size_t)nblk * PB;        // E
    unsigned short* h116 = (unsigned short*)regD;

    unsigned short* msg0  = (unsigned short*)d_out;
    unsigned char*  feat8 = (unsigned char*)d_out + (size_t)N * D * 2;
    unsigned char*  h18   = (unsigned char*)d_out + (size_t)N * D * 3;
    unsigned short* msg1F = feat16;   // feat16 dead after layer 0
    (void)ws_size;

    const int gemm_blocks = (N + 127) / 128;
    const int g16_blocks  = (N + 15) / 16;      // 6250

    // --- zero bucketCnt, then fused prep + coarse count ---
    hipMemsetAsync(bucketCnt, 0, 512 * 4, stream);
    prep_count_kernel<<<PREP_BLKS + nblk, 256, 0, stream>>>(
        feat, feat16, feat8, Ws0, Wn0, Ws1, Wn1, wt0, wt1,
        edst, bucketCnt, blockBase, E);

    // --- partitioned CSR build ---
    part_scan_kernel<<<1, 512, 0, stream>>>(bucketCnt, bucketStart, E);
    part_scatter_kernel<<<nblk, 256, 0, stream>>>(esrc, edst, bucketStart, blockBase, pairs, E);
    part_fine_kernel<<<PB, 256, 0, stream>>>(pairs, bucketStart, row_ptr, col, N, E);

    // --- Layer 0 ---
    gather16f_kernel<<<g16_blocks, 256, 0, stream>>>(feat8, row_ptr, col, indeg, msg0, N);
    mfma32_ln_kernel<<<gemm_blocks, 256, 0, stream>>>(
        feat16, msg0, wt0, b0, lng, lnb, h116, h18, N);

    // --- Layer 1 ---
    gather16f_kernel<<<g16_blocks, 256, 0, stream>>>(h18, row_ptr, col, indeg, msg1F, N);
    mfma32_f32_kernel<<<gemm_blocks, 256, 0, stream>>>(h116, msg1F, wt1, b1, out, N);
}

// Round 11
// 302.260 us; speedup vs baseline: 1.1146x; 1.1146x over previous
//
#include <hip/hip_runtime.h>

#define D 128
#define NN 100000
#define PB 391          // coarse buckets: dst >> 8
#define EPB 4096        // edges per partition block (r8 proved 1024 regresses)
#define PREP_BLKS 6506  // 6250 cvt + 256 wt

typedef __attribute__((ext_vector_type(8))) short short8;
typedef __attribute__((ext_vector_type(16))) float floatx16;
typedef __attribute__((ext_vector_type(2))) float floatx2;

__device__ inline unsigned short bf16_rne(float f) {
    unsigned int u = __float_as_uint(f);
    u += 0x7fff + ((u >> 16) & 1);
    return (unsigned short)(u >> 16);
}
__device__ inline unsigned char fp8_enc1(float f) {
    return (unsigned char)(__builtin_amdgcn_cvt_pk_fp8_f32(f, f, 0, false) & 0xff);
}

// async 16B global->LDS. LDS dest is wave-uniform base + lane*16 (hardware);
// our B table is already in the exact linear order -> identity staging.
__device__ inline void gload_lds16(const void* g, void* l) {
    __builtin_amdgcn_global_load_lds(
        (const __attribute__((address_space(1))) unsigned int*)g,
        (__attribute__((address_space(3))) unsigned int*)l, 16, 0, 0);
}

// ---------------------------------------------------------------------------
// F-layout (MFMA A-fragment order) for a [N][128] bf16 matrix:
//   F(n,d) = (n>>5)*4096 + ((d>>3)*32 + (n&31))*8 + (d&7)      [elements]
// A-fragment load for 32x32x16 MFMA is tile_base + kc*512 + lane*8 ->
// linear 1KB coalesced wave load.
//
// LESSONS ENCODED:
//  * r5: write regions must be dispatch-disjoint from read regions.
//  * r6: gather is latency-bound -> needs MANY blocks (TLP), not fusion.
//  * r7: gather FETCH ~79MB compulsory (XCD replication); near random floor.
//  * r8: EPB=1024 regressed prep_count 2x -> EPB=4096.
//  * r9/r10: K-loop matrix: {A-loop,B-glob}=40, {A-hoist,B-glob}=48 (VGPR 76
//    -> B 3-deep starved), {A-scat-hoist,B-LDS}=51. r11 tests the missing
//    cell {A-linear-hoist, B-LDS}: NO global latency inside the K-loop.
// ---------------------------------------------------------------------------

// Fused prep+count: [0,6250) cvt feat->bf16(F-layout)+fp8 | [6250,6506)
// build Wt in B-fragment order | [6506, 6506+nblk) coarse edge count.
__global__ __launch_bounds__(256) void prep_count_kernel(
    const float* __restrict__ feat, unsigned short* __restrict__ feat16,
    unsigned char* __restrict__ feat8,
    const float* __restrict__ Ws0, const float* __restrict__ Wn0,
    const float* __restrict__ Ws1, const float* __restrict__ Wn1,
    unsigned short* __restrict__ wt0, unsigned short* __restrict__ wt1,
    const int* __restrict__ dst, unsigned int* __restrict__ bucketCnt,
    unsigned int* __restrict__ blockBase, int E)
{
    __shared__ unsigned int h[PB];
    int bid = blockIdx.x;
    if (bid < 6250) {
        int i = bid * 256 + threadIdx.x;      // 0..1.6M  (n*16 + c8)
        int n  = i >> 4;
        int c8 = i & 15;                      // 8-elem chunk within row
        const float* src = feat + (size_t)n * D + c8 * 8;
        float4 v0 = *(const float4*)(src);
        float4 v1 = *(const float4*)(src + 4);
        unsigned short us[8] = {
            bf16_rne(v0.x), bf16_rne(v0.y), bf16_rne(v0.z), bf16_rne(v0.w),
            bf16_rne(v1.x), bf16_rne(v1.y), bf16_rne(v1.z), bf16_rne(v1.w) };
        // F-layout: d = c8*8 -> (d>>3)=c8, d&7 spans the 16B chunk
        size_t fo = (size_t)(n >> 5) * 4096 + ((size_t)c8 * 32 + (n & 31)) * 8;
        *(uint4*)(feat16 + fo) = *(const uint4*)us;
        int w0 = __builtin_amdgcn_cvt_pk_fp8_f32(v0.x, v0.y, 0, false);
        w0 = __builtin_amdgcn_cvt_pk_fp8_f32(v0.z, v0.w, w0, true);
        int w1 = __builtin_amdgcn_cvt_pk_fp8_f32(v1.x, v1.y, 0, false);
        w1 = __builtin_amdgcn_cvt_pk_fp8_f32(v1.z, v1.w, w1, true);
        uint2 w = { (unsigned int)w0, (unsigned int)w1 };
        *(uint2*)(feat8 + (size_t)n * D + c8 * 8) = w;   // row-major, coalesced
    } else if (bid < PREP_BLKS) {
        int i = (bid - 6250) * 256 + threadIdx.x;        // 0..65535
        int layer = i >> 15;
        int r = i & 32767;
        int n = r >> 8;
        int k = r & 255;
        const float* Ws = layer ? Ws1 : Ws0;
        const float* Wn = layer ? Wn1 : Wn0;
        float v = (k < 128) ? Ws[(size_t)k * 128 + n] : Wn[(size_t)(k - 128) * 128 + n];
        unsigned short* wt = layer ? wt1 : wt0;
        // B-fragment order
        int ct = n >> 5, nn = n & 31;
        int hs = k >> 7, k7 = k & 127;
        int kc = k7 >> 4, hf = (k7 >> 3) & 1, j = k7 & 7;
        int frag = ((((ct * 2 + hs) * 8 + kc) * 2 + hf) * 32 + nn) * 8 + j;
        wt[frag] = bf16_rne(v);
    } else {
        const int b = bid - PREP_BLKS;
        const int t = threadIdx.x;
        for (int i = t; i < PB; i += 256) h[i] = 0;
        __syncthreads();
        const int base = b * EPB;
#pragma unroll
        for (int k = 0; k < EPB / 256; k++) {
            int e = base + k * 256 + t;
            if (e < E) atomicAdd(&h[(unsigned)dst[e] >> 8], 1u);
        }
        __syncthreads();
        for (int i = t; i < PB; i += 256) {
            unsigned int c = h[i];
            unsigned int o = 0;
            if (c) o = atomicAdd(&bucketCnt[i], c);
            blockBase[(size_t)b * PB + i] = o;
        }
    }
}

// single block: exclusive scan of PB bucket counts -> bucketStart[PB+1]
__global__ __launch_bounds__(512) void part_scan_kernel(
    const unsigned int* __restrict__ bucketCnt, unsigned int* __restrict__ bucketStart,
    int E)
{
    __shared__ unsigned int sd[512];
    int t = threadIdx.x;
    unsigned int v = (t < PB) ? bucketCnt[t] : 0u;
    sd[t] = v; __syncthreads();
    for (int off = 1; off < 512; off <<= 1) {
        unsigned int x = (t >= off) ? sd[t - off] : 0u;
        __syncthreads();
        sd[t] += x;
        __syncthreads();
    }
    if (t < PB) bucketStart[t] = sd[t] - v;
    if (t == 0) bucketStart[PB] = (unsigned int)E;
}

// P2: scatter packed (src<<8 | dst&255) into bucket regions; ranks via LDS.
__global__ __launch_bounds__(256) void part_scatter_kernel(
    const int* __restrict__ src, const int* __restrict__ dst,
    const unsigned int* __restrict__ bucketStart,
    const unsigned int* __restrict__ blockBase,
    unsigned int* __restrict__ pairs, int E)
{
    __shared__ unsigned int h[PB];
    const int t = threadIdx.x;
    const int b = blockIdx.x;
    for (int i = t; i < PB; i += 256) h[i] = 0;
    __syncthreads();
    const int base = b * EPB;
#pragma unroll
    for (int k = 0; k < EPB / 256; k++) {
        int e = base + k * 256 + t;
        if (e < E) {
            unsigned int d = (unsigned int)dst[e];
            unsigned int bk = d >> 8;
            unsigned int lr = atomicAdd(&h[bk], 1u);
            unsigned int pos = bucketStart[bk] + blockBase[(size_t)b * PB + bk] + lr;
            pairs[pos] = ((unsigned int)src[e] << 8) | (d & 255u);
        }
    }
}

// P3: per-bucket fine CSR (256 dsts): LDS hist + scan -> row_ptr, cursor -> col.
__global__ __launch_bounds__(256) void part_fine_kernel(
    const unsigned int* __restrict__ pairs, const unsigned int* __restrict__ bucketStart,
    int* __restrict__ row_ptr, int* __restrict__ col, int N, int E)
{
    __shared__ unsigned int h[256], sc[256], pos[256];
    const int t = threadIdx.x;
    const int b = blockIdx.x;
    h[t] = 0;
    __syncthreads();
    const unsigned int ebeg = bucketStart[b];
    const unsigned int eend = bucketStart[b + 1];
    for (unsigned int i = ebeg + t; i < eend; i += 256)
        atomicAdd(&h[pairs[i] & 255u], 1u);
    __syncthreads();
    sc[t] = h[t]; __syncthreads();
    for (int off = 1; off < 256; off <<= 1) {
        unsigned int x = (t >= off) ? sc[t - off] : 0u;
        __syncthreads();
        sc[t] += x;
        __syncthreads();
    }
    unsigned int excl = sc[t] - h[t];
    int node = b * 256 + t;
    if (node < N) row_ptr[node] = (int)(ebeg + excl);
    pos[t] = ebeg + excl;
    if (b == 0 && t == 0) row_ptr[N] = E;
    __syncthreads();
    for (unsigned int i = ebeg + t; i < eend; i += 256) {
        unsigned int p = pairs[i];
        unsigned int w = atomicAdd(&pos[p & 255u], 1u);
        col[w] = (int)(p >> 8);
    }
}

// ---------------------------------------------------------------------------
// Gather -> F-layout, 16 nodes/block (6250 blocks), one node per 16-lane
// group, NO LDS / NO barrier. 8-deep load batches + packed floatx2 accum.
// Direct 16B F-store per lane.
// ---------------------------------------------------------------------------
__global__ __launch_bounds__(256, 6) void gather16f_kernel(
    const unsigned char* __restrict__ h8, const int* __restrict__ row_ptr,
    const int* __restrict__ col, const int* __restrict__ in_deg,
    unsigned short* __restrict__ msg16, int N)   // msg16: F-layout base
{
    const int tid  = threadIdx.x;
    const int nq   = tid >> 4;        // 0..15
    const int ln16 = tid & 15;
    const int node = blockIdx.x * 16 + nq;
    if (node >= N) return;
    const size_t lo = (size_t)ln16 * 8;   // byte offset within 128B fp8 row

    int beg = row_ptr[node];
    int end = row_ptr[node + 1];

    floatx2 a0 = {0.f, 0.f}, a1 = {0.f, 0.f}, a2 = {0.f, 0.f}, a3 = {0.f, 0.f};
    int j = beg;
    for (; j + 8 <= end; j += 8) {
        int c0 = col[j],     c1 = col[j + 1], c2 = col[j + 2], c3 = col[j + 3];
        int c4 = col[j + 4], c5 = col[j + 5], c6 = col[j + 6], c7 = col[j + 7];
        uint2 u0 = *(const uint2*)(h8 + (size_t)c0 * D + lo);
        uint2 u1 = *(const uint2*)(h8 + (size_t)c1 * D + lo);
        uint2 u2 = *(const uint2*)(h8 + (size_t)c2 * D + lo);
        uint2 u3 = *(const uint2*)(h8 + (size_t)c3 * D + lo);
        uint2 u4 = *(const uint2*)(h8 + (size_t)c4 * D + lo);
        uint2 u5 = *(const uint2*)(h8 + (size_t)c5 * D + lo);
        uint2 u6 = *(const uint2*)(h8 + (size_t)c6 * D + lo);
        uint2 u7 = *(const uint2*)(h8 + (size_t)c7 * D + lo);
#pragma unroll
        for (int q = 0; q < 8; q++) {
            uint2 u = q == 0 ? u0 : q == 1 ? u1 : q == 2 ? u2 : q == 3 ? u3
                    : q == 4 ? u4 : q == 5 ? u5 : q == 6 ? u6 : u7;
            a0 += __builtin_amdgcn_cvt_pk_f32_fp8((int)u.x, false);
            a1 += __builtin_amdgcn_cvt_pk_f32_fp8((int)u.x, true);
            a2 += __builtin_amdgcn_cvt_pk_f32_fp8((int)u.y, false);
            a3 += __builtin_amdgcn_cvt_pk_f32_fp8((int)u.y, true);
        }
    }
    for (; j + 4 <= end; j += 4) {
        int c0 = col[j], c1 = col[j + 1], c2 = col[j + 2], c3 = col[j + 3];
        uint2 u0 = *(const uint2*)(h8 + (size_t)c0 * D + lo);
        uint2 u1 = *(const uint2*)(h8 + (size_t)c1 * D + lo);
        uint2 u2 = *(const uint2*)(h8 + (size_t)c2 * D + lo);
        uint2 u3 = *(const uint2*)(h8 + (size_t)c3 * D + lo);
#pragma unroll
        for (int q = 0; q < 4; q++) {
            uint2 u = q == 0 ? u0 : q == 1 ? u1 : q == 2 ? u2 : u3;
            a0 += __builtin_amdgcn_cvt_pk_f32_fp8((int)u.x, false);
            a1 += __builtin_amdgcn_cvt_pk_f32_fp8((int)u.x, true);
            a2 += __builtin_amdgcn_cvt_pk_f32_fp8((int)u.y, false);
            a3 += __builtin_amdgcn_cvt_pk_f32_fp8((int)u.y, true);
        }
    }
    for (; j < end; ++j) {
        uint2 u = *(const uint2*)(h8 + (size_t)col[j] * D + lo);
        a0 += __builtin_amdgcn_cvt_pk_f32_fp8((int)u.x, false);
        a1 += __builtin_amdgcn_cvt_pk_f32_fp8((int)u.x, true);
        a2 += __builtin_amdgcn_cvt_pk_f32_fp8((int)u.y, false);
        a3 += __builtin_amdgcn_cvt_pk_f32_fp8((int)u.y, true);
    }

    int dg = in_deg[node];
    float invd = 1.f / (float)(dg > 1 ? dg : 1);
    unsigned short us[8];
    us[0] = bf16_rne(a0.x * invd); us[1] = bf16_rne(a0.y * invd);
    us[2] = bf16_rne(a1.x * invd); us[3] = bf16_rne(a1.y * invd);
    us[4] = bf16_rne(a2.x * invd); us[5] = bf16_rne(a2.y * invd);
    us[6] = bf16_rne(a3.x * invd); us[7] = bf16_rne(a3.y * invd);
    // F-layout store: d0 = ln16*8 -> (d0>>3)=ln16, j contiguous
    size_t fo = (size_t)(node >> 5) * 4096 + ((size_t)ln16 * 32 + (node & 31)) * 8;
    *(uint4*)(msg16 + fo) = *(const uint4*)us;
}

// ---------------------------------------------------------------------------
// Layer-0 MFMA dual-GEMM + LN/ReLU. r11: memory-wait-free K-loop —
//  * B staged once/block into LDS via linear global_load_lds (identity
//    mapping: table is already fragment-ordered; r3-verified, 0 conflicts).
//  * A's 16 fragments hoisted as linear 1KB loads (r10 piece); (256,2) so
//    VGPRs don't starve (r10's failure mode: cap 170 -> B 3-deep).
//  * One __syncthreads drain, then 64x {ds_read_b128 + MFMA}: LDS+regs only.
//  * LN epilogue reuses smem[0,48K) after a barrier (B dead).
// C/D: col=lane&31, row=(reg&3)+8*(reg>>2)+4*(lane>>5).
// ---------------------------------------------------------------------------
__global__ __launch_bounds__(256, 2) void mfma32_ln_kernel(
    const unsigned short* __restrict__ A16, const unsigned short* __restrict__ Msg16,
    const unsigned short* __restrict__ Wt,   // B-fragment order, 32768 bf16
    const float* __restrict__ bias,
    const float* __restrict__ ln_g, const float* __restrict__ ln_b,
    unsigned short* __restrict__ Out16, unsigned char* __restrict__ Out8,
    int N)
{
    __shared__ char smem[65536];   // B table; epilogue reuses [0,48K)

    const int tid  = threadIdx.x;
    const int wave = tid >> 6;
    const int lane = tid & 63;
    const int half = lane >> 5;
    const int n32  = lane & 31;
    const int brow0 = blockIdx.x * 128;
    const int wrow0 = brow0 + wave * 32;

    // ---- stage B (64KB, identity linear mapping) ----
    {
        const char* g = (const char*)Wt;
        char* ldst = smem + wave * 1024;           // wave-uniform dest base
#pragma unroll
        for (int i = 0; i < 16; i++)
            gload_lds16(g + ((size_t)(i * 256 + tid)) * 16, ldst + i * 4096);
    }

    const int NT = N >> 5;
    int tile = wrow0 >> 5;
    if (tile >= NT) tile = NT - 1;           // clamp: stores guarded below
    const short8* Af = (const short8*)(A16   + (size_t)tile * 4096);
    const short8* Mf = (const short8*)(Msg16 + (size_t)tile * 4096);

    // ---- hoist all 16 A-fragments: independent coalesced 1KB loads ----
    short8 a0[8], a1[8];
#pragma unroll
    for (int kc = 0; kc < 8; kc++) a0[kc] = Af[kc * 64 + lane];
#pragma unroll
    for (int kc = 0; kc < 8; kc++) a1[kc] = Mf[kc * 64 + lane];
    asm volatile("" ::: "memory");

    floatx16 acc[4];
#pragma unroll
    for (int ct = 0; ct < 4; ct++)
#pragma unroll
        for (int r = 0; r < 16; r++) acc[ct][r] = 0.f;

    __syncthreads();   // drain: B staged + a[] resident

    // ---- K-loop: LDS + registers only ----
#pragma unroll
    for (int kc = 0; kc < 8; kc++)
#pragma unroll
        for (int ct = 0; ct < 4; ct++) {
            short8 b = *(const short8*)(smem + ((size_t)(((ct * 2 + 0) * 8 + kc) * 64 + lane)) * 16);
            acc[ct] = __builtin_amdgcn_mfma_f32_32x32x16_bf16(a0[kc], b, acc[ct], 0, 0, 0);
        }
#pragma unroll
    for (int kc = 0; kc < 8; kc++)
#pragma unroll
        for (int ct = 0; ct < 4; ct++) {
            short8 b = *(const short8*)(smem + ((size_t)(((ct * 2 + 1) * 8 + kc) * 64 + lane)) * 16);
            acc[ct] = __builtin_amdgcn_mfma_f32_32x32x16_bf16(a1[kc], b, acc[ct], 0, 0, 0);
        }

    float bb[4], gg[4], be[4];
#pragma unroll
    for (int ct = 0; ct < 4; ct++) {
        bb[ct] = bias[ct * 32 + n32];
        gg[ct] = ln_g[ct * 32 + n32];
        be[ct] = ln_b[ct * 32 + n32];
    }
    float v[4][16];
#pragma unroll
    for (int ct = 0; ct < 4; ct++)
#pragma unroll
        for (int r = 0; r < 16; r++) v[ct][r] = acc[ct][r] + bb[ct];

    float s[16], s2[16];
#pragma unroll
    for (int r = 0; r < 16; r++) {
        s[r]  = v[0][r] + v[1][r] + v[2][r] + v[3][r];
        s2[r] = v[0][r]*v[0][r] + v[1][r]*v[1][r] + v[2][r]*v[2][r] + v[3][r]*v[3][r];
    }
#pragma unroll
    for (int off = 1; off < 32; off <<= 1) {
#pragma unroll
        for (int r = 0; r < 16; r++) {
            s[r]  += __shfl_xor(s[r],  off);
            s2[r] += __shfl_xor(s2[r], off);
        }
    }
    __syncthreads();   // all waves done reading B; reuse smem as staging
    unsigned char* sO8 = (unsigned char*)smem + 32768;       // [128][128] byte
#pragma unroll
    for (int r = 0; r < 16; r++) {
        float mean = s[r] * (1.f / 128.f);
        float var  = s2[r] * (1.f / 128.f) - mean * mean;
        float rstd = rsqrtf(var + 1e-5f);
        int brow = wave * 32 + (r & 3) + 8 * (r >> 2) + 4 * half;
#pragma unroll
        for (int ct = 0; ct < 4; ct++) {
            float t = (v[ct][r] - mean) * rstd * gg[ct] + be[ct];
            t = t > 0.f ? t : 0.f;
            // sO16 in F-order with XOR slot swizzle (conflict-free 2B writes)
            int slot = (ct * 4 + (n32 >> 3)) ^ (brow & 15);
            *(unsigned short*)(smem + brow * 256 + slot * 16 + (n32 & 7) * 2) = bf16_rne(t);
            sO8[brow * 128 + ct * 32 + n32] = fp8_enc1(t);
        }
    }
    __syncthreads();
    // Out16 (F-layout): linear global writes; LDS reads de-swizzled
#pragma unroll
    for (int i = 0; i < 8; i++) {                 // 2048 uint4 chunks
        int ch = tid + i * 256;
        int tl = ch >> 9, p = ch & 511, kc2 = p >> 5, rr = p & 31;
        if (brow0 + tl * 32 + rr < N)
            *(uint4*)(Out16 + (size_t)brow0 * D + ch * 8) =
                *(const uint4*)&smem[(tl * 32 + rr) * 256 + ((kc2 ^ (rr & 15)) * 16)];
    }
#pragma unroll
    for (int i = 0; i < 4; i++) {                 // fp8: 1024 uint4 chunks
        int ch = tid + i * 256;
        if (brow0 + (ch >> 3) < N)
            *(uint4*)(Out8 + (size_t)brow0 * D + ch * 16) = *(const uint4*)&sO8[ch * 16];
    }
}

// ---------------------------------------------------------------------------
// Layer-1 MFMA dual-GEMM, fp32 out: same memory-wait-free K-loop (B in LDS,
// A hoisted linear), (256,2). Direct full-128B-line stores, no epilogue LDS.
// ---------------------------------------------------------------------------
__global__ __launch_bounds__(256, 2) void mfma32_f32_kernel(
    const unsigned short* __restrict__ A16, const unsigned short* __restrict__ Msg16,
    const unsigned short* __restrict__ Wt,
    const float* __restrict__ bias,
    float* __restrict__ Out32, int N)
{
    __shared__ char smem[65536];   // B table

    const int tid  = threadIdx.x;
    const int wave = tid >> 6;
    const int lane = tid & 63;
    const int half = lane >> 5;
    const int n32  = lane & 31;
    const int brow0 = blockIdx.x * 128;
    const int wrow0 = brow0 + wave * 32;

    // ---- stage B (64KB, identity linear mapping) ----
    {
        const char* g = (const char*)Wt;
        char* ldst = smem + wave * 1024;
#pragma unroll
        for (int i = 0; i < 16; i++)
            gload_lds16(g + ((size_t)(i * 256 + tid)) * 16, ldst + i * 4096);
    }

    const int NT = N >> 5;
    int tile = wrow0 >> 5;
    if (tile >= NT) tile = NT - 1;
    const short8* Af = (const short8*)(A16   + (size_t)tile * 4096);
    const short8* Mf = (const short8*)(Msg16 + (size_t)tile * 4096);

    // ---- hoist all 16 A-fragments ----
    short8 a0[8], a1[8];
#pragma unroll
    for (int kc = 0; kc < 8; kc++) a0[kc] = Af[kc * 64 + lane];
#pragma unroll
    for (int kc = 0; kc < 8; kc++) a1[kc] = Mf[kc * 64 + lane];
    asm volatile("" ::: "memory");

    floatx16 acc[4];
#pragma unroll
    for (int ct = 0; ct < 4; ct++)
#pragma unroll
        for (int r = 0; r < 16; r++) acc[ct][r] = 0.f;

    __syncthreads();   // drain: B staged + a[] resident

    // ---- K-loop: LDS + registers only ----
#pragma unroll
    for (int kc = 0; kc < 8; kc++)
#pragma unroll
        for (int ct = 0; ct < 4; ct++) {
            short8 b = *(const short8*)(smem + ((size_t)(((ct * 2 + 0) * 8 + kc) * 64 + lane)) * 16);
            acc[ct] = __builtin_amdgcn_mfma_f32_32x32x16_bf16(a0[kc], b, acc[ct], 0, 0, 0);
        }
#pragma unroll
    for (int kc = 0; kc < 8; kc++)
#pragma unroll
        for (int ct = 0; ct < 4; ct++) {
            short8 b = *(const short8*)(smem + ((size_t)(((ct * 2 + 1) * 8 + kc) * 64 + lane)) * 16);
            acc[ct] = __builtin_amdgcn_mfma_f32_32x32x16_bf16(a1[kc], b, acc[ct], 0, 0, 0);
        }

    float bb[4];
#pragma unroll
    for (int ct = 0; ct < 4; ct++) bb[ct] = bias[ct * 32 + n32];

#pragma unroll
    for (int r = 0; r < 16; r++) {
        int row = wrow0 + (r & 3) + 8 * (r >> 2) + 4 * half;
        if (row < N) {
#pragma unroll
            for (int ct = 0; ct < 4; ct++)
                Out32[(size_t)row * D + ct * 32 + n32] = acc[ct][r] + bb[ct];
        }
    }
}

// ---------------------------------------------------------------------------
extern "C" void kernel_launch(void* const* d_in, const int* in_sizes, int n_in,
                              void* d_out, int out_size, void* d_ws, size_t ws_size,
                              hipStream_t stream)
{
    const float* feat = (const float*)d_in[0];
    const float* Ws0  = (const float*)d_in[1];
    const float* Wn0  = (const float*)d_in[2];
    const float* b0   = (const float*)d_in[3];
    const float* Ws1  = (const float*)d_in[4];
    const float* Wn1  = (const float*)d_in[5];
    const float* b1   = (const float*)d_in[6];
    const float* lng  = (const float*)d_in[7];
    const float* lnb  = (const float*)d_in[8];
    const int* esrc   = (const int*)d_in[9];
    const int* edst   = (const int*)d_in[10];
    const int* indeg  = (const int*)d_in[11];

    const int N = NN;
    const int E = in_sizes[9];

    float* out = (float*)d_out;

    // ws: feat16 | col | row_ptr | wt0 | wt1 | regD
    //   regD overlay (CSR build): bucketCnt | bucketStart | blockBase | pairs
    //   regD overlay (compute):   h1_16
    // d_out overlay (dead until final dispatch):
    //   [0,25.6M): msg0 | [25.6M,38.4M): feat8 | [38.4M,51.2M): h18
    // Dispatch-level safety (each line: reads -> writes, all disjoint):
    //   g16f L0:  feat8, CSR           -> msg0
    //   mfma L0:  feat16, msg0, wt0    -> h116(ws), h18
    //   g16f L1:  h18, CSR             -> msg1F (=feat16 region, dead)
    //   mfma L1:  h116, msg1F, wt1     -> out (msg0/feat8/h18 all dead)
    const int nblk = (E + EPB - 1) / EPB;
    char* ws = (char*)d_ws;
    size_t o = 0;
    auto alloc = [&](size_t bytes) { char* p = ws + o; o += (bytes + 15) & ~(size_t)15; return p; };
    unsigned short* feat16 = (unsigned short*)alloc((size_t)N * D * 2);
    int* col     = (int*)alloc((size_t)E * 4);
    int* row_ptr = (int*)alloc((size_t)(N + 1) * 4);
    unsigned short* wt0 = (unsigned short*)alloc(128 * 256 * 2);
    unsigned short* wt1 = (unsigned short*)alloc(128 * 256 * 2);
    size_t csr_bytes = (size_t)(512 + 512 + (size_t)nblk * PB + E) * 4 + 64;
    char* regD = alloc((size_t)N * D * 2 > csr_bytes ? (size_t)N * D * 2 : csr_bytes);
    unsigned int* bucketCnt   = (unsigned int*)regD;                  // 512 slots
    unsigned int* bucketStart = bucketCnt + 512;                      // 512 slots
    unsigned int* blockBase   = bucketStart + 512;                    // nblk*PB
    unsigned int* pairs       = blockBase + (size_t)nblk * PB;        // E
    unsigned short* h116 = (unsigned short*)regD;

    unsigned short* msg0  = (unsigned short*)d_out;
    unsigned char*  feat8 = (unsigned char*)d_out + (size_t)N * D * 2;
    unsigned char*  h18   = (unsigned char*)d_out + (size_t)N * D * 3;
    unsigned short* msg1F = feat16;   // feat16 dead after layer 0
    (void)ws_size;

    const int gemm_blocks = (N + 127) / 128;
    const int g16_blocks  = (N + 15) / 16;      // 6250

    // --- zero bucketCnt, then fused prep + coarse count ---
    hipMemsetAsync(bucketCnt, 0, 512 * 4, stream);
    prep_count_kernel<<<PREP_BLKS + nblk, 256, 0, stream>>>(
        feat, feat16, feat8, Ws0, Wn0, Ws1, Wn1, wt0, wt1,
        edst, bucketCnt, blockBase, E);

    // --- partitioned CSR build ---
    part_scan_kernel<<<1, 512, 0, stream>>>(bucketCnt, bucketStart, E);
    part_scatter_kernel<<<nblk, 256, 0, stream>>>(esrc, edst, bucketStart, blockBase, pairs, E);
    part_fine_kernel<<<PB, 256, 0, stream>>>(pairs, bucketStart, row_ptr, col, N, E);

    // --- Layer 0 ---
    gather16f_kernel<<<g16_blocks, 256, 0, stream>>>(feat8, row_ptr, col, indeg, msg0, N);
    mfma32_ln_kernel<<<gemm_blocks, 256, 0, stream>>>(
        feat16, msg0, wt0, b0, lng, lnb, h116, h18, N);

    // --- Layer 1 ---
    gather16f_kernel<<<g16_blocks, 256, 0, stream>>>(h18, row_ptr, col, indeg, msg1F, N);
    mfma32_f32_kernel<<<gemm_blocks, 256, 0, stream>>>(h116, msg1F, wt1, b1, out, N);
}